// Round 9
// baseline (882.712 us; speedup 1.0000x reference)
//
#include <hip/hip_runtime.h>
#include <hip/hip_fp16.h>

#define TOKENS 8192
#define INPUT  1024
#define HIDDEN 16384
#define KSEL   32
#define CANDCAP 96
#define TWO_E  0.012f

typedef __attribute__((ext_vector_type(8))) short bf16x8;
typedef __attribute__((ext_vector_type(4))) float f32x4;

#define GLOAD_LDS16(g, l) __builtin_amdgcn_global_load_lds(              \
    (const __attribute__((address_space(1))) void*)(const void*)(g),     \
    (__attribute__((address_space(3))) void*)(void*)(l), 16, 0, 0)

__device__ inline short f2bf(float f) {
    unsigned u = __float_as_uint(f);
    u += 0x7FFFu + ((u >> 16) & 1u);   // RNE
    return (short)(u >> 16);
}

__device__ inline float keyToF(unsigned k) {
    unsigned o = (k & 0x8000u) ? (k ^ 0x8000u) : (~k & 0xFFFFu);
    return __half2float(__ushort_as_half((unsigned short)o));
}

// ---------------- Abf = bf16(x - peb) ----------------
__global__ __launch_bounds__(256) void conv_x(
    const float* __restrict__ x, const float* __restrict__ peb,
    short* __restrict__ Abf)
{
    const int g = (blockIdx.x * 256 + threadIdx.x) * 8;
    const int col = g & (INPUT - 1);
    float4 v0 = *(const float4*)&x[g];
    float4 v1 = *(const float4*)&x[g + 4];
    float4 p0 = *(const float4*)&peb[col];
    float4 p1 = *(const float4*)&peb[col + 4];
    short o[8] = {f2bf(v0.x - p0.x), f2bf(v0.y - p0.y), f2bf(v0.z - p0.z), f2bf(v0.w - p0.w),
                  f2bf(v1.x - p1.x), f2bf(v1.y - p1.y), f2bf(v1.z - p1.z), f2bf(v1.w - p1.w)};
    *(bf16x8*)&Abf[g] = *(bf16x8*)o;
}

// ---------------- Transpose WT -> WTT[HIDDEN][INPUT] fp32 AND Btb bf16 ----------------
__global__ __launch_bounds__(256) void transp2(
    const float* __restrict__ WT, float* __restrict__ WTT, short* __restrict__ Btb)
{
    __shared__ float tl[64][65];
    const int bx = blockIdx.x, by = blockIdx.y;
    const int tid = threadIdx.x;
    const int r0 = tid >> 6, c = tid & 63;
#pragma unroll
    for (int i = 0; i < 16; ++i) {
        int r = i * 4 + r0;
        tl[r][c] = WT[(size_t)(by * 64 + r) * HIDDEN + bx * 64 + c];
    }
    __syncthreads();
#pragma unroll
    for (int i = 0; i < 16; ++i) {
        int a = i * 4 + r0;
        float v = tl[c][a];
        size_t o = (size_t)(bx * 64 + a) * INPUT + by * 64 + c;
        WTT[o] = v;
        Btb[o] = f2bf(v);
    }
}

// ---------------- Whf = fp16(W) ----------------
__global__ __launch_bounds__(256) void conv_whf(
    const float* __restrict__ W, unsigned short* __restrict__ Whf)
{
    const size_t g = ((size_t)blockIdx.x * 256 + threadIdx.x) * 8;
    float4 v0 = *(const float4*)&W[g];
    float4 v1 = *(const float4*)&W[g + 4];
    unsigned short o[8] = {
        __half_as_ushort(__float2half(v0.x)), __half_as_ushort(__float2half(v0.y)),
        __half_as_ushort(__float2half(v0.z)), __half_as_ushort(__float2half(v0.w)),
        __half_as_ushort(__float2half(v1.x)), __half_as_ushort(__float2half(v1.y)),
        __half_as_ushort(__float2half(v1.z)), __half_as_ushort(__float2half(v1.w))};
    *(uint4*)&Whf[g] = *(uint4*)o;
}

// ---------------- 256x256 bf16 MFMA GEMM, triple-buffer depth-2 prefetch ----------------
// pre16 = fp16(Abf @ Btb^T + b1). 8 waves (2Mx4N, 128x64/wave), BK=32, 96 KiB LDS.
// vmcnt(8): waited-on loads are 2 iterations old. Epilogue via LDS transpose.
__global__ __launch_bounds__(512, 2) void gemm_bf16_256(
    const short* __restrict__ A,   // [TOKENS][INPUT] bf16
    const short* __restrict__ Bt,  // [HIDDEN][INPUT] bf16
    const float* __restrict__ bias1,
    unsigned short* __restrict__ pre16, // [chunkM][HIDDEN] fp16
    int tok0)
{
    __shared__ short lds[49152]; // 3 buffers x 32KB (A 8192 shorts + B 8192 shorts)
    const int tid = threadIdx.x;
    const int lane = tid & 63;
    const int w = tid >> 6;
    const int wr = w >> 2, wc = w & 3;   // 2M x 4N waves

    // bijective XCD swizzle (nwg = 64 * My, always % 8 == 0)
    const int nbx = gridDim.x;
    const int nwg = nbx * gridDim.y;
    int flat = blockIdx.y * nbx + blockIdx.x;
    flat = (flat & 7) * (nwg >> 3) + (flat >> 3);
    const int bn = flat % nbx, bm = flat / nbx;

    const int row0 = tok0 + bm * 256;
    const int col0 = bn * 256;

    // staging source map: region byte dd -> logical (row, bf16-col) via involution
    auto srcmap = [&](int dd, int& r, int& cb) {
        int sub = dd >> 10, win = dd & 1023;
        int uw = win ^ (((win >> 8) & 3) << 4);
        r = sub * 16 + (uw >> 6);
        cb = (uw & 63) >> 1;
    };
    int rA0, cA0, rA1, cA1;
    srcmap(tid * 16, rA0, cA0);
    srcmap(8192 + tid * 16, rA1, cA1);
    const short* pA0 = A  + (size_t)(row0 + rA0) * INPUT + cA0;
    const short* pA1 = A  + (size_t)(row0 + rA1) * INPUT + cA1;
    const short* pB0 = Bt + (size_t)(col0 + rA0) * INPUT + cA0;
    const short* pB1 = Bt + (size_t)(col0 + rA1) * INPUT + cA1;

    // frag read offsets (shorts, within region)
    int aoff[8], boff[4];
    const int cbyteK = (lane >> 4) * 16;
#pragma unroll
    for (int mf = 0; mf < 8; ++mf) {
        int r = wr * 128 + mf * 16 + (lane & 15);
        int wi = (r & 15) * 64 + cbyteK;
        wi ^= ((wi >> 8) & 3) << 4;
        aoff[mf] = (r >> 4) * 512 + (wi >> 1);
    }
#pragma unroll
    for (int nf = 0; nf < 4; ++nf) {
        int r = wc * 64 + nf * 16 + (lane & 15);
        int wi = (r & 15) * 64 + cbyteK;
        wi ^= ((wi >> 8) & 3) << 4;
        boff[nf] = (r >> 4) * 512 + (wi >> 1);
    }

    f32x4 acc[8][4];
#pragma unroll
    for (int m = 0; m < 8; ++m)
#pragma unroll
        for (int n = 0; n < 4; ++n) acc[m][n] = (f32x4){0.f, 0.f, 0.f, 0.f};

    auto stage = [&](int kt, short* buf) {
        const int kb = kt * 32;
        GLOAD_LDS16(pA0 + kb, buf + tid * 8);
        GLOAD_LDS16(pA1 + kb, buf + 4096 + tid * 8);
        GLOAD_LDS16(pB0 + kb, buf + 8192 + tid * 8);
        GLOAD_LDS16(pB1 + kb, buf + 12288 + tid * 8);
    };

    const int NT = INPUT / 32; // 32
    short *bc = lds, *bn1 = lds + 16384, *bn2 = lds + 32768;
    stage(0, bc);
    stage(1, bn1);

    for (int kt = 0; kt < NT; ++kt) {
        if (kt < NT - 2) {
            stage(kt + 2, bn2);
            asm volatile("s_waitcnt vmcnt(8)" ::: "memory");
        } else if (kt == NT - 2) {
            asm volatile("s_waitcnt vmcnt(4)" ::: "memory");
        } else {
            asm volatile("s_waitcnt vmcnt(0)" ::: "memory");
        }
        asm volatile("s_barrier" ::: "memory");

#pragma unroll
        for (int q = 0; q < 4; ++q) {
            const int qr = q >> 1, qc = q & 1;    // mf 0-3/4-7, nf 0-1/2-3
            bf16x8 af[4], bfm[2];
#pragma unroll
            for (int i = 0; i < 4; ++i) af[i] = *(const bf16x8*)&bc[aoff[qr * 4 + i]];
#pragma unroll
            for (int j = 0; j < 2; ++j) bfm[j] = *(const bf16x8*)&bc[8192 + boff[qc * 2 + j]];
            __builtin_amdgcn_s_setprio(1);
#pragma unroll
            for (int i = 0; i < 4; ++i)
#pragma unroll
                for (int j = 0; j < 2; ++j)
                    acc[qr * 4 + i][qc * 2 + j] = __builtin_amdgcn_mfma_f32_16x16x32_bf16(
                        af[i], bfm[j], acc[qr * 4 + i][qc * 2 + j], 0, 0, 0);
            __builtin_amdgcn_s_setprio(0);
        }
        asm volatile("s_waitcnt lgkmcnt(0)\ns_barrier" ::: "memory");
        short* t = bc; bc = bn1; bn1 = bn2; bn2 = t;
    }

    // ---- epilogue: bias + fp16, LDS transpose to coalesced 512B stores ----
    float bb[4];
#pragma unroll
    for (int nf = 0; nf < 4; ++nf)
        bb[nf] = bias1[col0 + wc * 64 + nf * 16 + (lane & 15)];

    unsigned short* LE = (unsigned short*)lds; // [32][264]
#pragma unroll
    for (int mf = 0; mf < 8; ++mf) {
#pragma unroll
        for (int nf = 0; nf < 4; ++nf) {
#pragma unroll
            for (int r = 0; r < 4; ++r) {
                int er = wr * 16 + (lane >> 4) * 4 + r;
                int ec = wc * 64 + nf * 16 + (lane & 15);
                LE[er * 264 + ec] = __half_as_ushort(__float2half(acc[mf][nf][r] + bb[nf]));
            }
        }
        __syncthreads();
#pragma unroll
        for (int rd = 0; rd < 2; ++rd) {
            int idx = rd * 512 + tid;
            int er = idx >> 5, c8 = (idx & 31) * 8;
            int b = er >> 4;
            int grow = bm * 256 + b * 128 + mf * 16 + (er & 15);
            uint4 v = *(const uint4*)&LE[er * 264 + c8];
            *(uint4*)&pre16[(size_t)grow * HIDDEN + col0 + c8] = v;
        }
        __syncthreads();
    }
}

// ---------------- Candidate select on fp16 keys; widened threshold; deterministic ----------------
__global__ __launch_bounds__(256) void topcand3(
    const unsigned short* __restrict__ pre16, // [chunkM][HIDDEN] fp16
    int* __restrict__ cand,  // [TOKENS][CANDCAP]
    float* __restrict__ scr, // [TOKENS][CANDCAP] screen values
    int* __restrict__ ncand, // [TOKENS]
    int tok0)
{
    const int tid = threadIdx.x;
    const int t = blockIdx.x;
    const unsigned short* row = pre16 + (size_t)t * HIDDEN;

    unsigned pk[32];
#pragma unroll
    for (int i = 0; i < 8; ++i) {
        uint4 raw = *(const uint4*)&row[(size_t)tid * 64 + i * 8];
        unsigned rr[4] = {raw.x, raw.y, raw.z, raw.w};
#pragma unroll
        for (int j = 0; j < 4; ++j) {
            unsigned lo16 = rr[j] & 0xFFFFu, hi16 = rr[j] >> 16;
            lo16 ^= (((lo16 >> 15) * 0xFFFFu) | 0x8000u);
            hi16 ^= (((hi16 >> 15) * 0xFFFFu) | 0x8000u);
            pk[i * 4 + j] = lo16 | (hi16 << 16);
        }
    }

    __shared__ unsigned wsum[4];
    const int lane = tid & 63, wid = tid >> 6;

    auto countGE = [&](unsigned tau) -> unsigned {
        unsigned c = 0;
#pragma unroll
        for (int i = 0; i < 32; ++i) {
            c += ((pk[i] & 0xFFFFu) >= tau) ? 1u : 0u;
            c += ((pk[i] >> 16) >= tau) ? 1u : 0u;
        }
#pragma unroll
        for (int s = 32; s > 0; s >>= 1) c += __shfl_xor(c, s, 64);
        if (lane == 0) wsum[wid] = c;
        __syncthreads();
        unsigned tot = wsum[0] + wsum[1] + wsum[2] + wsum[3];
        __syncthreads();
        return tot;
    };

    unsigned lo = 0, hi = 0xFFFFu;
    for (int it = 0; it < 17 && lo < hi; ++it) {
        unsigned mid = (lo + hi + 1) >> 1;
        unsigned c = countGE(mid);
        if (c >= 40u) { lo = mid; if (c <= 48u) break; }
        else hi = mid - 1;
    }
    float v40 = keyToF(lo);
    float vthr = v40 - (TWO_E + 0.002f);
    unsigned kthr = (unsigned)__half_as_ushort(__float2half(vthr));
    kthr ^= (((kthr >> 15) * 0xFFFFu) | 0x8000u);

    __shared__ unsigned short cnts[256];
    unsigned mycnt = 0;
#pragma unroll
    for (int i = 0; i < 32; ++i) {
        mycnt += ((pk[i] & 0xFFFFu) >= kthr) ? 1u : 0u;
        mycnt += ((pk[i] >> 16) >= kthr) ? 1u : 0u;
    }
    cnts[tid] = (unsigned short)mycnt;
    __syncthreads();
    unsigned base = 0, tot = 0;
    for (int k = 0; k < 256; ++k) {
        unsigned ck = cnts[k];
        if (k < tid) base += ck;
        tot += ck;
    }
    const int gtok = tok0 + t;
    unsigned pos = base;
#pragma unroll
    for (int i = 0; i < 32; ++i) {
        unsigned l16 = pk[i] & 0xFFFFu, h16 = pk[i] >> 16;
        if (l16 >= kthr) {
            if (pos < CANDCAP) {
                cand[(size_t)gtok * CANDCAP + pos] = tid * 64 + i * 2;
                scr[(size_t)gtok * CANDCAP + pos] = keyToF(l16);
            }
            ++pos;
        }
        if (h16 >= kthr) {
            if (pos < CANDCAP) {
                cand[(size_t)gtok * CANDCAP + pos] = tid * 64 + i * 2 + 1;
                scr[(size_t)gtok * CANDCAP + pos] = keyToF(h16);
            }
            ++pos;
        }
    }
    if (tid == 0) ncand[gtok] = (int)(tot < (unsigned)CANDCAP ? tot : (unsigned)CANDCAP);
}

// ---------------- Band f64 rescore -> exact selection -> fp16 decode, fused ----------------
__global__ __launch_bounds__(256) void rescore_band_decode(
    const float* __restrict__ x, const float* __restrict__ peb,
    const float* __restrict__ WTT, const float* __restrict__ bias1,
    const int* __restrict__ cand, const float* __restrict__ scr,
    const int* __restrict__ ncand,
    const unsigned short* __restrict__ Whf, const float* __restrict__ b2,
    float* __restrict__ out)
{
    const int t = blockIdx.x;
    const int tid = threadIdx.x;
    __shared__ double xcs[INPUT];
    __shared__ float sv[CANDCAP];
    __shared__ int   si[CANDCAP];
    __shared__ double bex[CANDCAP];
    __shared__ unsigned char flg[CANDCAP];
    __shared__ unsigned char self_[CANDCAP];
    __shared__ short bandlist[CANDCAP];
    __shared__ float s32s;
    __shared__ int bns, nins;
    __shared__ float sel_v[KSEL];
    __shared__ int sel_i[KSEL];

    const int nc0 = ncand[t];
    const int nc = nc0 < CANDCAP ? nc0 : CANDCAP;

#pragma unroll
    for (int i = 0; i < 4; ++i) {
        int j = tid + i * 256;
        xcs[j] = (double)x[(size_t)t * INPUT + j] - (double)peb[j];
    }
    if (tid < nc) {
        sv[tid] = scr[(size_t)t * CANDCAP + tid];
        si[tid] = cand[(size_t)t * CANDCAP + tid];
    }
    __syncthreads();

    if (tid < nc) {
        float v = sv[tid]; int h = si[tid];
        int r = 0;
        for (int k = 0; k < nc; ++k) {
            float vk = sv[k];
            if (vk > v || (vk == v && si[k] < h)) ++r;
        }
        if (r == 31) s32s = v;
    }
    __syncthreads();
    const float s32 = s32s;

    if (tid < nc) {
        float v = sv[tid];
        flg[tid] = (v > s32 + TWO_E) ? 2 : ((v >= s32 - TWO_E) ? 1 : 0);
    }
    __syncthreads();
    if (tid == 0) {
        int bn = 0, nin = 0;
        for (int k = 0; k < nc; ++k) {
            if (flg[k] == 1) bandlist[bn++] = (short)k;
            else if (flg[k] == 2) ++nin;
        }
        bns = bn; nins = nin;
    }
    __syncthreads();
    const int bn = bns, need = KSEL - nins;

    const int wid = tid >> 6, lane = tid & 63;
    for (int j0 = wid * 2; j0 < bn; j0 += 8) {
        const int j1 = j0 + 1;
        const int c0 = bandlist[j0];
        const int c1 = (j1 < bn) ? bandlist[j1] : c0;
        const int h0 = si[c0], h1 = si[c1];
        const float* w0 = WTT + (size_t)h0 * INPUT;
        const float* w1 = WTT + (size_t)h1 * INPUT;
        double s0 = 0.0, s1 = 0.0;
#pragma unroll
        for (int st = 0; st < 16; ++st) {
            const double xv = xcs[lane + st * 64];
            s0 += (double)w0[lane + st * 64] * xv;
            s1 += (double)w1[lane + st * 64] * xv;
        }
#pragma unroll
        for (int off = 32; off > 0; off >>= 1) {
            s0 += __shfl_xor(s0, off, 64);
            s1 += __shfl_xor(s1, off, 64);
        }
        if (lane == 0) {
            bex[c0] = s0 + (double)bias1[h0];
            if (j1 < bn) bex[c1] = s1 + (double)bias1[h1];
        }
    }
    __syncthreads();

    if (tid < nc) {
        int s = 0;
        if (flg[tid] == 2) s = 1;
        else if (flg[tid] == 1) {
            double v = bex[tid]; int h = si[tid];
            int r = 0;
            for (int k = 0; k < bn; ++k) {
                int ck = bandlist[k];
                double vk = bex[ck];
                if (vk > v || (vk == v && si[ck] < h)) ++r;
            }
            if (r < need) s = 1;
        }
        self_[tid] = (unsigned char)s;
    }
    __syncthreads();
    if (tid < nc && self_[tid]) {
        int pos = 0;
        for (int k = 0; k < tid; ++k) pos += self_[k];
        if (pos < KSEL) {
            sel_v[pos] = (flg[tid] == 2) ? sv[tid] : (float)bex[tid];
            sel_i[pos] = si[tid];
        }
    }
    __syncthreads();

    const int c = tid * 4;
    float4 acc = *(const float4*)&b2[c];
#pragma unroll 8
    for (int j = 0; j < KSEL; ++j) {
        const int h = sel_i[j];
        uint2 raw = *(const uint2*)&Whf[(size_t)h * INPUT + c];
        const float s = sel_v[j];
        __half2 p0 = *(__half2*)&raw.x;
        __half2 p1 = *(__half2*)&raw.y;
        float2 f0 = __half22float2(p0);
        float2 f1 = __half22float2(p1);
        acc.x += s * f0.x; acc.y += s * f0.y; acc.z += s * f1.x; acc.w += s * f1.y;
    }
    *(float4*)&out[(size_t)t * INPUT + c] = acc;
}

extern "C" void kernel_launch(void* const* d_in, const int* in_sizes, int n_in,
                              void* d_out, int out_size, void* d_ws, size_t ws_size,
                              hipStream_t stream) {
    const float* x   = (const float*)d_in[0];
    const float* peb = (const float*)d_in[1];
    const float* W   = (const float*)d_in[2];
    const float* WT  = (const float*)d_in[3];
    const float* b1  = (const float*)d_in[4];
    const float* b2  = (const float*)d_in[5];
    float* out = (float*)d_out;

    char* p = (char*)d_ws;
    int*   candb = (int*)p;            p += (size_t)TOKENS * CANDCAP * 4;
    float* scrb  = (float*)p;          p += (size_t)TOKENS * CANDCAP * 4;
    int*   ncb   = (int*)p;            p += (size_t)TOKENS * 4;
    float* WTT   = (float*)p;          p += (size_t)HIDDEN * INPUT * 4;
    short* Abf   = (short*)p;          p += (size_t)TOKENS * INPUT * 2;
    short* Btb   = (short*)p;          p += (size_t)HIDDEN * INPUT * 2;
    unsigned short* Whf = (unsigned short*)p; p += (size_t)HIDDEN * INPUT * 2;
    unsigned short* pre16 = (unsigned short*)p;

    size_t used = (size_t)(p - (char*)d_ws);
    size_t avail = ws_size > used ? ws_size - used : 0;
    long cap = (long)(avail / ((size_t)HIDDEN * 2));
    cap = (cap / 256) * 256;
    if (cap > TOKENS) cap = TOKENS;
    if (cap < 256) cap = 256;

    conv_x<<<dim3(TOKENS * INPUT / (256 * 8)), dim3(256), 0, stream>>>(x, peb, Abf);
    transp2<<<dim3(HIDDEN / 64, INPUT / 64), dim3(256), 0, stream>>>(WT, WTT, Btb);
    conv_whf<<<dim3((unsigned)((size_t)HIDDEN * INPUT / (256 * 8))), dim3(256), 0, stream>>>(W, Whf);

    for (int tok0 = 0; tok0 < TOKENS; tok0 += (int)cap) {
        int M = TOKENS - tok0;
        if (M > cap) M = (int)cap;
        gemm_bf16_256<<<dim3(HIDDEN / 256, M / 256), dim3(512), 0, stream>>>(
            Abf, Btb, b1, pre16, tok0);
        topcand3<<<dim3(M), dim3(256), 0, stream>>>(pre16, candb, scrb, ncb, tok0);
    }

    rescore_band_decode<<<dim3(TOKENS), dim3(256), 0, stream>>>(
        x, peb, WTT, b1, candb, scrb, ncb, Whf, b2, out);
}

// Round 10
// 815.262 us; speedup vs baseline: 1.0827x; 1.0827x over previous
//
#include <hip/hip_runtime.h>
#include <hip/hip_fp16.h>

#define TOKENS 8192
#define INPUT  1024
#define HIDDEN 16384
#define KSEL   32
#define CANDCAP 96
#define TWO_E  0.012f

typedef __attribute__((ext_vector_type(8))) short bf16x8;
typedef __attribute__((ext_vector_type(4))) float f32x4;

#define GLOAD_LDS16(g, l) __builtin_amdgcn_global_load_lds(              \
    (const __attribute__((address_space(1))) void*)(const void*)(g),     \
    (__attribute__((address_space(3))) void*)(void*)(l), 16, 0, 0)

__device__ inline short f2bf(float f) {
    unsigned u = __float_as_uint(f);
    u += 0x7FFFu + ((u >> 16) & 1u);   // RNE
    return (short)(u >> 16);
}

__device__ inline float keyToF(unsigned k) {
    unsigned o = (k & 0x8000u) ? (k ^ 0x8000u) : (~k & 0xFFFFu);
    return __half2float(__ushort_as_half((unsigned short)o));
}

// ---------------- Abf = bf16(x - peb) ----------------
__global__ __launch_bounds__(256) void conv_x(
    const float* __restrict__ x, const float* __restrict__ peb,
    short* __restrict__ Abf)
{
    const int g = (blockIdx.x * 256 + threadIdx.x) * 8;
    const int col = g & (INPUT - 1);
    float4 v0 = *(const float4*)&x[g];
    float4 v1 = *(const float4*)&x[g + 4];
    float4 p0 = *(const float4*)&peb[col];
    float4 p1 = *(const float4*)&peb[col + 4];
    short o[8] = {f2bf(v0.x - p0.x), f2bf(v0.y - p0.y), f2bf(v0.z - p0.z), f2bf(v0.w - p0.w),
                  f2bf(v1.x - p1.x), f2bf(v1.y - p1.y), f2bf(v1.z - p1.z), f2bf(v1.w - p1.w)};
    *(bf16x8*)&Abf[g] = *(bf16x8*)o;
}

// ---------------- Transpose WT -> WTT[HIDDEN][INPUT] fp32 AND Btb bf16 ----------------
__global__ __launch_bounds__(256) void transp2(
    const float* __restrict__ WT, float* __restrict__ WTT, short* __restrict__ Btb)
{
    __shared__ float tl[64][65];
    const int bx = blockIdx.x, by = blockIdx.y;
    const int tid = threadIdx.x;
    const int r0 = tid >> 6, c = tid & 63;
#pragma unroll
    for (int i = 0; i < 16; ++i) {
        int r = i * 4 + r0;
        tl[r][c] = WT[(size_t)(by * 64 + r) * HIDDEN + bx * 64 + c];
    }
    __syncthreads();
#pragma unroll
    for (int i = 0; i < 16; ++i) {
        int a = i * 4 + r0;
        float v = tl[c][a];
        size_t o = (size_t)(bx * 64 + a) * INPUT + by * 64 + c;
        WTT[o] = v;
        Btb[o] = f2bf(v);
    }
}

// ---------------- Whf = fp16(W) ----------------
__global__ __launch_bounds__(256) void conv_whf(
    const float* __restrict__ W, unsigned short* __restrict__ Whf)
{
    const size_t g = ((size_t)blockIdx.x * 256 + threadIdx.x) * 8;
    float4 v0 = *(const float4*)&W[g];
    float4 v1 = *(const float4*)&W[g + 4];
    unsigned short o[8] = {
        __half_as_ushort(__float2half(v0.x)), __half_as_ushort(__float2half(v0.y)),
        __half_as_ushort(__float2half(v0.z)), __half_as_ushort(__float2half(v0.w)),
        __half_as_ushort(__float2half(v1.x)), __half_as_ushort(__float2half(v1.y)),
        __half_as_ushort(__float2half(v1.z)), __half_as_ushort(__float2half(v1.w))};
    *(uint4*)&Whf[g] = *(uint4*)o;
}

// ---------------- 256x256 bf16 MFMA GEMM ----------------
// 8 waves (2Mx4N, 128x64/wave), BK=32, 4 LDS buffers (128 KiB), depth-2
// prefetch, ONE barrier per K-iter, 12 distinct b128 frag reads per iter.
__global__ __launch_bounds__(512, 2) void gemm_bf16_256(
    const short* __restrict__ A,   // [TOKENS][INPUT] bf16
    const short* __restrict__ Bt,  // [HIDDEN][INPUT] bf16
    const float* __restrict__ bias1,
    unsigned short* __restrict__ pre16, // [chunkM][HIDDEN] fp16
    int tok0)
{
    __shared__ short lds[65536]; // 4 buffers x 32KB (A 16KB + B 16KB)
    const int tid = threadIdx.x;
    const int lane = tid & 63;
    const int w = tid >> 6;
    const int wr = w >> 2, wc = w & 3;   // 2M x 4N waves

    // bijective XCD swizzle (nwg = 64 * My, always % 8 == 0)
    const int nbx = gridDim.x;
    const int nwg = nbx * gridDim.y;
    int flat = blockIdx.y * nbx + blockIdx.x;
    flat = (flat & 7) * (nwg >> 3) + (flat >> 3);
    const int bn = flat % nbx, bm = flat / nbx;

    const int row0 = tok0 + bm * 256;
    const int col0 = bn * 256;

    // staging: dest linear, source pre-inverse-swizzled (involution)
    int dstA[2], dstB[2];
    const short *srcA[2], *srcB[2];
#pragma unroll
    for (int l = 0; l < 2; ++l) {
        int d = l * 8192 + tid * 16;          // byte within 16KB region
        int sub = d >> 10, win = d & 1023;
        int uw = win ^ (((win >> 8) & 3) << 4);
        int r = sub * 16 + (uw >> 6);
        int cb = (uw & 63) >> 1;
        dstA[l] = d >> 1;
        dstB[l] = 8192 + (d >> 1);
        srcA[l] = A  + (size_t)(row0 + r) * INPUT + cb;
        srcB[l] = Bt + (size_t)(col0 + r) * INPUT + cb;
    }

    // frag read offsets (shorts within buffer)
    int aoff[8], boff[4];
    const int cbyteK = (lane >> 4) * 16;
#pragma unroll
    for (int mf = 0; mf < 8; ++mf) {
        int r = wr * 128 + mf * 16 + (lane & 15);
        int wi = (r & 15) * 64 + cbyteK;
        wi ^= ((wi >> 8) & 3) << 4;
        aoff[mf] = (r >> 4) * 512 + (wi >> 1);
    }
#pragma unroll
    for (int nf = 0; nf < 4; ++nf) {
        int r = wc * 64 + nf * 16 + (lane & 15);
        int wi = (r & 15) * 64 + cbyteK;
        wi ^= ((wi >> 8) & 3) << 4;
        boff[nf] = 8192 + (r >> 4) * 512 + (wi >> 1);
    }

    f32x4 acc[8][4];
#pragma unroll
    for (int m = 0; m < 8; ++m)
#pragma unroll
        for (int n = 0; n < 4; ++n) acc[m][n] = (f32x4){0.f, 0.f, 0.f, 0.f};

    auto stage = [&](int kt) {
        short* buf = &lds[(kt & 3) * 16384];
        const int kb = kt * 32;
        GLOAD_LDS16(srcA[0] + kb, buf + dstA[0]);
        GLOAD_LDS16(srcA[1] + kb, buf + dstA[1]);
        GLOAD_LDS16(srcB[0] + kb, buf + dstB[0]);
        GLOAD_LDS16(srcB[1] + kb, buf + dstB[1]);
    };

    const int NT = INPUT / 32; // 32
    stage(0);
    stage(1);

    for (int j = 0; j < NT; ++j) {
        const short* buf = &lds[(j & 3) * 16384];
        if (j < NT - 1) {
            asm volatile("s_waitcnt vmcnt(4)" ::: "memory"); // tile j landed
        } else {
            asm volatile("s_waitcnt vmcnt(0)" ::: "memory");
        }
        __builtin_amdgcn_s_barrier();

        bf16x8 af[8], bfm[4];
#pragma unroll
        for (int mf = 0; mf < 8; ++mf) af[mf] = *(const bf16x8*)&buf[aoff[mf]];
#pragma unroll
        for (int nf = 0; nf < 4; ++nf) bfm[nf] = *(const bf16x8*)&buf[boff[nf]];

        if (j < NT - 2) stage(j + 2); // issues under MFMA shadow; buffer j-2 safe

        __builtin_amdgcn_s_setprio(1);
#pragma unroll
        for (int mf = 0; mf < 8; ++mf)
#pragma unroll
            for (int nf = 0; nf < 4; ++nf)
                acc[mf][nf] = __builtin_amdgcn_mfma_f32_16x16x32_bf16(
                    af[mf], bfm[nf], acc[mf][nf], 0, 0, 0);
        __builtin_amdgcn_s_setprio(0);
    }

    __syncthreads(); // drain before reusing LDS for the epilogue

    // ---- epilogue: bias + fp16, LDS transpose to coalesced 512B stores ----
    float bb[4];
#pragma unroll
    for (int nf = 0; nf < 4; ++nf)
        bb[nf] = bias1[col0 + wc * 64 + nf * 16 + (lane & 15)];

    unsigned short* LE = (unsigned short*)lds; // [32][264]
#pragma unroll
    for (int mf = 0; mf < 8; ++mf) {
#pragma unroll
        for (int nf = 0; nf < 4; ++nf) {
#pragma unroll
            for (int r = 0; r < 4; ++r) {
                int er = wr * 16 + (lane >> 4) * 4 + r;
                int ec = wc * 64 + nf * 16 + (lane & 15);
                LE[er * 264 + ec] = __half_as_ushort(__float2half(acc[mf][nf][r] + bb[nf]));
            }
        }
        __syncthreads();
#pragma unroll
        for (int rd = 0; rd < 2; ++rd) {
            int idx = rd * 512 + tid;
            int er = idx >> 5, c8 = (idx & 31) * 8;
            int b = er >> 4;
            int grow = bm * 256 + b * 128 + mf * 16 + (er & 15);
            uint4 v = *(const uint4*)&LE[er * 264 + c8];
            *(uint4*)&pre16[(size_t)grow * HIDDEN + col0 + c8] = v;
        }
        __syncthreads();
    }
}

// ---------------- Candidate select on fp16 keys; widened threshold; deterministic ----------------
__global__ __launch_bounds__(256) void topcand3(
    const unsigned short* __restrict__ pre16, // [chunkM][HIDDEN] fp16
    int* __restrict__ cand,  // [TOKENS][CANDCAP]
    float* __restrict__ scr, // [TOKENS][CANDCAP] screen values
    int* __restrict__ ncand, // [TOKENS]
    int tok0)
{
    const int tid = threadIdx.x;
    const int t = blockIdx.x;
    const unsigned short* row = pre16 + (size_t)t * HIDDEN;

    unsigned pk[32];
#pragma unroll
    for (int i = 0; i < 8; ++i) {
        uint4 raw = *(const uint4*)&row[(size_t)tid * 64 + i * 8];
        unsigned rr[4] = {raw.x, raw.y, raw.z, raw.w};
#pragma unroll
        for (int j = 0; j < 4; ++j) {
            unsigned lo16 = rr[j] & 0xFFFFu, hi16 = rr[j] >> 16;
            lo16 ^= (((lo16 >> 15) * 0xFFFFu) | 0x8000u);
            hi16 ^= (((hi16 >> 15) * 0xFFFFu) | 0x8000u);
            pk[i * 4 + j] = lo16 | (hi16 << 16);
        }
    }

    __shared__ unsigned wsum[4];
    const int lane = tid & 63, wid = tid >> 6;

    auto countGE = [&](unsigned tau) -> unsigned {
        unsigned c = 0;
#pragma unroll
        for (int i = 0; i < 32; ++i) {
            c += ((pk[i] & 0xFFFFu) >= tau) ? 1u : 0u;
            c += ((pk[i] >> 16) >= tau) ? 1u : 0u;
        }
#pragma unroll
        for (int s = 32; s > 0; s >>= 1) c += __shfl_xor(c, s, 64);
        if (lane == 0) wsum[wid] = c;
        __syncthreads();
        unsigned tot = wsum[0] + wsum[1] + wsum[2] + wsum[3];
        __syncthreads();
        return tot;
    };

    unsigned lo = 0, hi = 0xFFFFu;
    for (int it = 0; it < 17 && lo < hi; ++it) {
        unsigned mid = (lo + hi + 1) >> 1;
        unsigned c = countGE(mid);
        if (c >= 40u) { lo = mid; if (c <= 48u) break; }
        else hi = mid - 1;
    }
    float v40 = keyToF(lo);
    float vthr = v40 - (TWO_E + 0.002f);
    unsigned kthr = (unsigned)__half_as_ushort(__float2half(vthr));
    kthr ^= (((kthr >> 15) * 0xFFFFu) | 0x8000u);

    __shared__ unsigned short cnts[256];
    unsigned mycnt = 0;
#pragma unroll
    for (int i = 0; i < 32; ++i) {
        mycnt += ((pk[i] & 0xFFFFu) >= kthr) ? 1u : 0u;
        mycnt += ((pk[i] >> 16) >= kthr) ? 1u : 0u;
    }
    cnts[tid] = (unsigned short)mycnt;
    __syncthreads();
    unsigned base = 0, tot = 0;
    for (int k = 0; k < 256; ++k) {
        unsigned ck = cnts[k];
        if (k < tid) base += ck;
        tot += ck;
    }
    const int gtok = tok0 + t;
    unsigned pos = base;
#pragma unroll
    for (int i = 0; i < 32; ++i) {
        unsigned l16 = pk[i] & 0xFFFFu, h16 = pk[i] >> 16;
        if (l16 >= kthr) {
            if (pos < CANDCAP) {
                cand[(size_t)gtok * CANDCAP + pos] = tid * 64 + i * 2;
                scr[(size_t)gtok * CANDCAP + pos] = keyToF(l16);
            }
            ++pos;
        }
        if (h16 >= kthr) {
            if (pos < CANDCAP) {
                cand[(size_t)gtok * CANDCAP + pos] = tid * 64 + i * 2 + 1;
                scr[(size_t)gtok * CANDCAP + pos] = keyToF(h16);
            }
            ++pos;
        }
    }
    if (tid == 0) ncand[gtok] = (int)(tot < (unsigned)CANDCAP ? tot : (unsigned)CANDCAP);
}

// ---------------- Band f64 rescore -> exact selection -> fp16 decode, fused ----------------
__global__ __launch_bounds__(256) void rescore_band_decode(
    const float* __restrict__ x, const float* __restrict__ peb,
    const float* __restrict__ WTT, const float* __restrict__ bias1,
    const int* __restrict__ cand, const float* __restrict__ scr,
    const int* __restrict__ ncand,
    const unsigned short* __restrict__ Whf, const float* __restrict__ b2,
    float* __restrict__ out)
{
    const int t = blockIdx.x;
    const int tid = threadIdx.x;
    __shared__ double xcs[INPUT];
    __shared__ float sv[CANDCAP];
    __shared__ int   si[CANDCAP];
    __shared__ double bex[CANDCAP];
    __shared__ unsigned char flg[CANDCAP];
    __shared__ unsigned char self_[CANDCAP];
    __shared__ short bandlist[CANDCAP];
    __shared__ float s32s;
    __shared__ int bns, nins;
    __shared__ float sel_v[KSEL];
    __shared__ int sel_i[KSEL];

    const int nc0 = ncand[t];
    const int nc = nc0 < CANDCAP ? nc0 : CANDCAP;

#pragma unroll
    for (int i = 0; i < 4; ++i) {
        int j = tid + i * 256;
        xcs[j] = (double)x[(size_t)t * INPUT + j] - (double)peb[j];
    }
    if (tid < nc) {
        sv[tid] = scr[(size_t)t * CANDCAP + tid];
        si[tid] = cand[(size_t)t * CANDCAP + tid];
    }
    __syncthreads();

    if (tid < nc) {
        float v = sv[tid]; int h = si[tid];
        int r = 0;
        for (int k = 0; k < nc; ++k) {
            float vk = sv[k];
            if (vk > v || (vk == v && si[k] < h)) ++r;
        }
        if (r == 31) s32s = v;
    }
    __syncthreads();
    const float s32 = s32s;

    if (tid < nc) {
        float v = sv[tid];
        flg[tid] = (v > s32 + TWO_E) ? 2 : ((v >= s32 - TWO_E) ? 1 : 0);
    }
    __syncthreads();
    if (tid == 0) {
        int bn = 0, nin = 0;
        for (int k = 0; k < nc; ++k) {
            if (flg[k] == 1) bandlist[bn++] = (short)k;
            else if (flg[k] == 2) ++nin;
        }
        bns = bn; nins = nin;
    }
    __syncthreads();
    const int bn = bns, need = KSEL - nins;

    const int wid = tid >> 6, lane = tid & 63;
    for (int j0 = wid * 2; j0 < bn; j0 += 8) {
        const int j1 = j0 + 1;
        const int c0 = bandlist[j0];
        const int c1 = (j1 < bn) ? bandlist[j1] : c0;
        const int h0 = si[c0], h1 = si[c1];
        const float* w0 = WTT + (size_t)h0 * INPUT;
        const float* w1 = WTT + (size_t)h1 * INPUT;
        double s0 = 0.0, s1 = 0.0;
#pragma unroll
        for (int st = 0; st < 16; ++st) {
            const double xv = xcs[lane + st * 64];
            s0 += (double)w0[lane + st * 64] * xv;
            s1 += (double)w1[lane + st * 64] * xv;
        }
#pragma unroll
        for (int off = 32; off > 0; off >>= 1) {
            s0 += __shfl_xor(s0, off, 64);
            s1 += __shfl_xor(s1, off, 64);
        }
        if (lane == 0) {
            bex[c0] = s0 + (double)bias1[h0];
            if (j1 < bn) bex[c1] = s1 + (double)bias1[h1];
        }
    }
    __syncthreads();

    if (tid < nc) {
        int s = 0;
        if (flg[tid] == 2) s = 1;
        else if (flg[tid] == 1) {
            double v = bex[tid]; int h = si[tid];
            int r = 0;
            for (int k = 0; k < bn; ++k) {
                int ck = bandlist[k];
                double vk = bex[ck];
                if (vk > v || (vk == v && si[ck] < h)) ++r;
            }
            if (r < need) s = 1;
        }
        self_[tid] = (unsigned char)s;
    }
    __syncthreads();
    if (tid < nc && self_[tid]) {
        int pos = 0;
        for (int k = 0; k < tid; ++k) pos += self_[k];
        if (pos < KSEL) {
            sel_v[pos] = (flg[tid] == 2) ? sv[tid] : (float)bex[tid];
            sel_i[pos] = si[tid];
        }
    }
    __syncthreads();

    const int c = tid * 4;
    float4 acc = *(const float4*)&b2[c];
#pragma unroll 8
    for (int j = 0; j < KSEL; ++j) {
        const int h = sel_i[j];
        uint2 raw = *(const uint2*)&Whf[(size_t)h * INPUT + c];
        const float s = sel_v[j];
        __half2 p0 = *(__half2*)&raw.x;
        __half2 p1 = *(__half2*)&raw.y;
        float2 f0 = __half22float2(p0);
        float2 f1 = __half22float2(p1);
        acc.x += s * f0.x; acc.y += s * f0.y; acc.z += s * f1.x; acc.w += s * f1.y;
    }
    *(float4*)&out[(size_t)t * INPUT + c] = acc;
}

extern "C" void kernel_launch(void* const* d_in, const int* in_sizes, int n_in,
                              void* d_out, int out_size, void* d_ws, size_t ws_size,
                              hipStream_t stream) {
    const float* x   = (const float*)d_in[0];
    const float* peb = (const float*)d_in[1];
    const float* W   = (const float*)d_in[2];
    const float* WT  = (const float*)d_in[3];
    const float* b1  = (const float*)d_in[4];
    const float* b2  = (const float*)d_in[5];
    float* out = (float*)d_out;

    char* p = (char*)d_ws;
    int*   candb = (int*)p;            p += (size_t)TOKENS * CANDCAP * 4;
    float* scrb  = (float*)p;          p += (size_t)TOKENS * CANDCAP * 4;
    int*   ncb   = (int*)p;            p += (size_t)TOKENS * 4;
    float* WTT   = (float*)p;          p += (size_t)HIDDEN * INPUT * 4;
    short* Abf   = (short*)p;          p += (size_t)TOKENS * INPUT * 2;
    short* Btb   = (short*)p;          p += (size_t)HIDDEN * INPUT * 2;
    unsigned short* Whf = (unsigned short*)p; p += (size_t)HIDDEN * INPUT * 2;
    unsigned short* pre16 = (unsigned short*)p;

    size_t used = (size_t)(p - (char*)d_ws);
    size_t avail = ws_size > used ? ws_size - used : 0;
    long cap = (long)(avail / ((size_t)HIDDEN * 2));
    cap = (cap / 256) * 256;
    if (cap > TOKENS) cap = TOKENS;
    if (cap < 256) cap = 256;

    conv_x<<<dim3(TOKENS * INPUT / (256 * 8)), dim3(256), 0, stream>>>(x, peb, Abf);
    transp2<<<dim3(HIDDEN / 64, INPUT / 64), dim3(256), 0, stream>>>(WT, WTT, Btb);
    conv_whf<<<dim3((unsigned)((size_t)HIDDEN * INPUT / (256 * 8))), dim3(256), 0, stream>>>(W, Whf);

    for (int tok0 = 0; tok0 < TOKENS; tok0 += (int)cap) {
        int M = TOKENS - tok0;
        if (M > cap) M = (int)cap;
        gemm_bf16_256<<<dim3(HIDDEN / 256, M / 256), dim3(512), 0, stream>>>(
            Abf, Btb, b1, pre16, tok0);
        topcand3<<<dim3(M), dim3(256), 0, stream>>>(pre16, candb, scrb, ncb, tok0);
    }

    rescore_band_decode<<<dim3(TOKENS), dim3(256), 0, stream>>>(
        x, peb, WTT, b1, candb, scrb, ncb, Whf, b2, out);
}